// Round 5
// baseline (403.790 us; speedup 1.0000x reference)
//
#include <hip/hip_runtime.h>
#include <hip/hip_bf16.h>
#include <math.h>

using bf16 = __hip_bfloat16;

#define PIF      3.14159265358979323846f
#define TWO_PIF  6.28318530717958647692f
#define BINW     0.52359877559829887308f   // 2*pi/12
#define HBINW    0.26179938779914943654f   // BINW*0.5

// ---------------------------------------------------------------------------
// Sentinel: signals host-side precondition failure through the absmax error.
// ---------------------------------------------------------------------------
__global__ void sentinel_kernel(float* out, float val) {
    out[0] = val;
}

// ---------------------------------------------------------------------------
// K0: transpose W1 of both heads into Wt[c][o] (o<256 = box row o of Wb1,
// o>=256 = cls row o-256 of Wc1). Grid (16,16), 256 threads, 32x32 tiles.
// ---------------------------------------------------------------------------
__global__ __launch_bounds__(256) void wt_kernel(
    const float* __restrict__ Wb1, const float* __restrict__ Wc1,
    float* __restrict__ Wt)               // [512][512]
{
    __shared__ float t[32][33];
    const int tx = threadIdx.x & 31;
    const int ty = threadIdx.x >> 5;      // 0..7
    const int c0 = blockIdx.x * 32;
    const int o0 = blockIdx.y * 32;
#pragma unroll
    for (int r = 0; r < 4; ++r) {
        const int o = o0 + ty + r * 8;
        const float* src = (o < 256) ? (Wb1 + (size_t)o * 512)
                                     : (Wc1 + (size_t)(o - 256) * 512);
        t[ty + r * 8][tx] = src[c0 + tx];
    }
    __syncthreads();
#pragma unroll
    for (int r = 0; r < 4; ++r) {
        const int c = c0 + ty + r * 8;
        Wt[(size_t)c * 512 + o0 + tx] = t[tx][ty + r * 8];
    }
}

// ---------------------------------------------------------------------------
// K1: fully fused heads: L1 (512->512 mids, both heads) in f32, h in LDS,
// L2 (33 outputs) + decode. Grid (128 n-tiles, 8 batches), 512 threads.
// LDS: sW 32K + sX 2K + sH 512*33*4 = 67.6K + sO 4.2K  ~= 106 KiB.
// ---------------------------------------------------------------------------
__global__ __launch_bounds__(512) void head_kernel(
    const float* __restrict__ x,          // [8][512][4096]
    const float* __restrict__ Wt,         // [512][512]  Wt[c][o]
    const float* __restrict__ bb1, const float* __restrict__ sb1,
    const float* __restrict__ tb1,
    const float* __restrict__ bc1, const float* __restrict__ sc1,
    const float* __restrict__ tc1,
    const float* __restrict__ Wb2, const float* __restrict__ bb2,
    const float* __restrict__ Wc2, const float* __restrict__ bc2,
    const float* __restrict__ ctr_preds,  // [8][4096][3]
    const float* __restrict__ mean_size,  // [3][3]
    float* __restrict__ out_box,   // [8][4096][30]
    float* __restrict__ out_cls,   // [8][4096][3]
    float* __restrict__ out_dec)   // [8][4096][7]
{
    __shared__ float sW[16 * 512];        // sW[k][o]
    __shared__ float sX[16 * 32];         // sX[k][n]
    __shared__ float sH[512 * 33];        // sH[o][n], padded to 33
    __shared__ float sO[33 * 32];         // sO[ja][n]

    const int tid = threadIdx.x;
    const int bz  = blockIdx.y;
    const int n0  = blockIdx.x * 32;

    const int ty = tid >> 2;              // 0..127 -> o = ty*4
    const int tx = tid & 3;               // 0..3   -> n = tx*8

    const int sw_k = tid >> 5;            // 0..15
    const int sw_o = (tid & 31) * 16;     // 16 floats per thread
    const int sx_k = tid >> 5;            // 0..15
    const int sx_n = tid & 31;            // 0..31

    const float* xb = x + (size_t)bz * 512 * 4096;

    float acc[4][8];
#pragma unroll
    for (int i = 0; i < 4; ++i)
#pragma unroll
        for (int j = 0; j < 8; ++j) acc[i][j] = 0.f;

    for (int c0 = 0; c0 < 512; c0 += 16) {
        // stage sW[k][o] = Wt[c0+k][o]  (coalesced: consecutive o)
#pragma unroll
        for (int r = 0; r < 4; ++r)
            *(float4*)&sW[sw_k * 512 + sw_o + r * 4] =
                *(const float4*)(Wt + (size_t)(c0 + sw_k) * 512 + sw_o + r * 4);
        // stage sX[k][n] = x[bz][c0+k][n0+n]  (coalesced)
        sX[sx_k * 32 + sx_n] = xb[(size_t)(c0 + sx_k) * 4096 + n0 + sx_n];
        __syncthreads();

#pragma unroll
        for (int k = 0; k < 16; ++k) {
            float a[4], b[8];
            *(float4*)&a[0] = *(const float4*)&sW[k * 512 + ty * 4];
            *(float4*)&b[0] = *(const float4*)&sX[k * 32 + tx * 8];
            *(float4*)&b[4] = *(const float4*)&sX[k * 32 + tx * 8 + 4];
#pragma unroll
            for (int i = 0; i < 4; ++i)
#pragma unroll
                for (int j = 0; j < 8; ++j)
                    acc[i][j] = fmaf(a[i], b[j], acc[i][j]);
        }
        __syncthreads();
    }

    // L1 epilogue: h = relu((acc + b1) * s1 + t1) -> sH (f32)
#pragma unroll
    for (int i = 0; i < 4; ++i) {
        const int o = ty * 4 + i;
        float bv, sv, tv;
        if (o < 256) { bv = bb1[o];       sv = sb1[o];       tv = tb1[o]; }
        else         { bv = bc1[o - 256]; sv = sc1[o - 256]; tv = tc1[o - 256]; }
        float hv[8];
#pragma unroll
        for (int j = 0; j < 8; ++j)
            hv[j] = fmaxf(fmaf(acc[i][j] + bv, sv, tv), 0.f);
        *(float4*)&sH[o * 33 + tx * 8]     = *(float4*)&hv[0];
        *(float4*)&sH[o * 33 + tx * 8 + 4] = *(float4*)&hv[4];
    }
    __syncthreads();

    // L2: sO[ja][n], ja 0..29 box (Wb2/bb2), 30..32 cls (Wc2/bc2)
    for (int p = tid; p < 33 * 32; p += 512) {
        const int ja = p >> 5;
        const int n  = p & 31;
        const float* w2; float bias; int hoff;
        if (ja < 30) { w2 = Wb2 + (size_t)ja * 256;        bias = bb2[ja];      hoff = 0;   }
        else         { w2 = Wc2 + (size_t)(ja - 30) * 256; bias = bc2[ja - 30]; hoff = 256; }
        float a2 = 0.f;
#pragma unroll 8
        for (int o = 0; o < 256; ++o)
            a2 = fmaf(w2[o], sH[(hoff + o) * 33 + n], a2);
        sO[ja * 32 + n] = a2 + bias;
    }
    __syncthreads();

    // epilogue + decode, 1 thread per point
    if (tid < 32) {
        const int nn = tid;
        const size_t gn = (size_t)bz * 4096 + n0 + nn;

        float* ob = out_box + gn * 30;
#pragma unroll
        for (int j = 0; j < 30; ++j) ob[j] = sO[j * 32 + nn];

        const float c0v = sO[30 * 32 + nn];
        const float c1v = sO[31 * 32 + nn];
        const float c2v = sO[32 * 32 + nn];
        out_cls[gn * 3 + 0] = c0v;
        out_cls[gn * 3 + 1] = c1v;
        out_cls[gn * 3 + 2] = c2v;

        int cl = 0; float bv = c0v;
        if (c1v > bv) { bv = c1v; cl = 1; }
        if (c2v > bv) { bv = c2v; cl = 2; }

        const float a0 = mean_size[cl * 3 + 0];
        const float a1 = mean_size[cl * 3 + 1];
        const float a2 = mean_size[cl * 3 + 2];
        const float diag = sqrtf(a0 * a0 + a1 * a1);

        const float px = ctr_preds[gn * 3 + 0];
        const float py = ctr_preds[gn * 3 + 1];
        const float pz = ctr_preds[gn * 3 + 2];

        const float cx = px + sO[0 * 32 + nn] * diag;
        const float cy = py + sO[1 * 32 + nn] * diag;
        const float cz = pz + sO[2 * 32 + nn] * a2;
        const float d0 = expf(sO[3 * 32 + nn]) * a0;
        const float d1 = expf(sO[4 * 32 + nn]) * a1;
        const float d2 = expf(sO[5 * 32 + nn]) * a2;

        int bbin = 0; float lb = sO[6 * 32 + nn];
        for (int k = 1; k < 12; ++k) {
            const float v = sO[(6 + k) * 32 + nn];
            if (v > lb) { lb = v; bbin = k; }
        }
        const float r   = sO[(18 + bbin) * 32 + nn];
        const float ang = ((float)bbin + 0.5f) * BINW + r * HBINW - PIF;

        float* od = out_dec + gn * 7;
        od[0] = cx; od[1] = cy; od[2] = cz;
        od[3] = d0; od[4] = d1; od[5] = d2;
        od[6] = ang;
    }
}

// ---------------------------------------------------------------------------
// K3: assign (points_in_boxes + gather/mask [+ encode]). f32 outputs.
// ---------------------------------------------------------------------------
__global__ __launch_bounds__(256) void assign_kernel(
    const float* __restrict__ pts, int Npts,
    const float* __restrict__ gt_boxes,   // [8][64][7]
    const int*   __restrict__ gt_labels,  // [8][64]
    const float* __restrict__ mean_size,  // [3][3]
    const float* __restrict__ ext,        // [3]
    int ignore, int retlab,
    float* __restrict__ out_idx, float* __restrict__ out_cls,
    float* __restrict__ out_fgb, float* __restrict__ out_lab)
{
    __shared__ float sc[64][4];
    __shared__ float srot[64][2];
    __shared__ float shr[64][4];
    __shared__ float she[64][4];
    __shared__ float sdim[64][4];
    __shared__ float sang[64];
    __shared__ int   slab[64];

    const int tid = threadIdx.x;
    const int b   = blockIdx.y;

    if (tid < 64) {
        const float* bx = gt_boxes + ((size_t)b * 64 + tid) * 7;
        const float cx = bx[0], cy = bx[1], cz = bx[2];
        const float d0 = bx[3], d1 = bx[4], d2 = bx[5], hd = bx[6];
        sc[tid][0] = cx; sc[tid][1] = cy; sc[tid][2] = cz;
        srot[tid][0] = cosf(hd); srot[tid][1] = sinf(hd);
        shr[tid][0] = d0 * 0.5f; shr[tid][1] = d1 * 0.5f; shr[tid][2] = d2 * 0.5f;
        she[tid][0] = (d0 + ext[0]) * 0.5f;
        she[tid][1] = (d1 + ext[1]) * 0.5f;
        she[tid][2] = (d2 + ext[2]) * 0.5f;
        sdim[tid][0] = d0; sdim[tid][1] = d1; sdim[tid][2] = d2;
        sang[tid] = hd;
        slab[tid] = gt_labels[b * 64 + tid];
    }
    __syncthreads();

    const int n = blockIdx.x * 256 + tid;
    if (n >= Npts) return;
    const size_t gp = (size_t)b * Npts + n;

    const float px = pts[gp * 3 + 0];
    const float py = pts[gp * 3 + 1];
    const float pz = pts[gp * 3 + 2];

    int idxr = -1, idxe = -1;
    for (int j = 0; j < 64; ++j) {
        const float rx = px - sc[j][0];
        const float ry = py - sc[j][1];
        const float rz = pz - sc[j][2];
        const float ct = srot[j][0], st = srot[j][1];
        const float lx = rx * ct + ry * st;
        const float ly = -rx * st + ry * ct;
        const float ax = fabsf(lx), ay = fabsf(ly), az = fabsf(rz);
        const bool inr = (ax <= shr[j][0]) && (ay <= shr[j][1]) && (az <= shr[j][2]);
        const bool ine = (ax <= she[j][0]) && (ay <= she[j][1]) && (az <= she[j][2]);
        if (inr && idxr < 0) idxr = j;
        if (ine && idxe < 0) idxe = j;
    }

    const bool fgr = idxr >= 0;
    const bool fge = idxe >= 0;
    int idx, cls;
    bool fg;
    if (ignore) {
        idx = idxr; fg = fgr;
        cls = (fgr != fge) ? -1 : 0;
    } else {
        idx = fgr ? idxr : idxe; fg = fge;
        cls = 0;
    }
    const int ic  = (idx < 0) ? 0 : idx;
    const int lab = slab[ic];
    if (fg) cls = lab;
    fg = fg && (cls != 0);

    out_idx[gp] = (float)idx;
    out_cls[gp] = (float)cls;

    const float m = fg ? 1.f : 0.f;
    float* fb = out_fgb + gp * 7;
    fb[0] = m * sc[ic][0];
    fb[1] = m * sc[ic][1];
    fb[2] = m * sc[ic][2];
    fb[3] = m * sdim[ic][0];
    fb[4] = m * sdim[ic][1];
    fb[5] = m * sdim[ic][2];
    fb[6] = m * sang[ic];

    if (retlab) {
        int lc = lab; if (lc < 1) lc = 1; if (lc > 3) lc = 3;
        const float a0 = mean_size[(lc - 1) * 3 + 0];
        const float a1 = mean_size[(lc - 1) * 3 + 1];
        const float a2 = mean_size[(lc - 1) * 3 + 2];
        const float diag = sqrtf(a0 * a0 + a1 * a1);

        const float ct0 = (sc[ic][0] - px) / diag;
        const float ct1 = (sc[ic][1] - py) / diag;
        const float ct2 = (sc[ic][2] - pz) / a2;
        const float dt0 = logf(fmaxf(sdim[ic][0], 0.001f) / a0);
        const float dt1 = logf(fmaxf(sdim[ic][1], 0.001f) / a1);
        const float dt2 = logf(fmaxf(sdim[ic][2], 0.001f) / a2);

        float angm = fmodf(sang[ic] + PIF, TWO_PIF);
        if (angm < 0.f) angm += TWO_PIF;
        float bbf = floorf(angm / BINW);
        bbf = fminf(fmaxf(bbf, 0.f), 11.f);
        const float rr = (angm - (bbf + 0.5f) * BINW) / HBINW;

        float* ol = out_lab + gp * 8;
        ol[0] = m * ct0;
        ol[1] = m * ct1;
        ol[2] = m * ct2;
        ol[3] = m * dt0;
        ol[4] = m * dt1;
        ol[5] = m * dt2;
        ol[6] = m * bbf;
        ol[7] = m * rr;
    }
}

// ---------------------------------------------------------------------------
extern "C" void kernel_launch(void* const* d_in, const int* in_sizes, int n_in,
                              void* d_out, int out_size, void* d_ws, size_t ws_size,
                              hipStream_t stream) {
    (void)out_size;

    static const int kExp[23] = {
        16777216, 98304, 98304, 393216, 98304, 3584, 512, 9, 3, 3, 3,
        131072, 256, 256, 256, 7680, 30, 131072, 256, 256, 256, 768, 3
    };
    bool ok = (n_in == 23);
    if (ok) for (int i = 0; i < 23; ++i) if (in_sizes[i] != kExp[i]) ok = false;
    if (!ok) {
        sentinel_kernel<<<1, 1, 0, stream>>>((float*)d_out, 1.0e6f);
        return;
    }
    if (ws_size < (size_t)512 * 512 * 4) {   // 1 MiB for Wt
        sentinel_kernel<<<1, 1, 0, stream>>>((float*)d_out, 2.0e6f);
        return;
    }

    const float* ctr_feats   = (const float*)d_in[0];
    const float* ctr_preds   = (const float*)d_in[1];
    const float* ctr_origins = (const float*)d_in[2];
    const float* sa_pts0     = (const float*)d_in[3];
    const float* sa_pts1     = (const float*)d_in[4];
    const float* gt_boxes    = (const float*)d_in[5];
    const int*   gt_labels   = (const int*)d_in[6];
    const float* mean_size   = (const float*)d_in[7];
    const float* gt_ext      = (const float*)d_in[8];
    const float* sa_ext      = (const float*)d_in[9];
    const float* org_ext     = (const float*)d_in[10];
    const float* Wb1 = (const float*)d_in[11];
    const float* bb1 = (const float*)d_in[12];
    const float* sb1 = (const float*)d_in[13];
    const float* tb1 = (const float*)d_in[14];
    const float* Wb2 = (const float*)d_in[15];
    const float* bb2 = (const float*)d_in[16];
    const float* Wc1 = (const float*)d_in[17];
    const float* bc1 = (const float*)d_in[18];
    const float* sc1 = (const float*)d_in[19];
    const float* tc1 = (const float*)d_in[20];
    const float* Wc2 = (const float*)d_in[21];
    const float* bc2 = (const float*)d_in[22];

    float* p = (float*)d_out;
    float* o_box  = p; p += (size_t)8 * 4096 * 30;
    float* o_cls  = p; p += (size_t)8 * 4096 * 3;
    float* o_dec  = p; p += (size_t)8 * 4096 * 7;
    float* a_idx  = p; p += (size_t)8 * 4096;
    float* a_cl   = p; p += (size_t)8 * 4096;
    float* a_fgb  = p; p += (size_t)8 * 4096 * 7;
    float* a_lab  = p; p += (size_t)8 * 4096 * 8;
    float* b_idx  = p; p += (size_t)8 * 4096;
    float* b_cl   = p; p += (size_t)8 * 4096;
    float* b_fgb  = p; p += (size_t)8 * 4096 * 7;
    float* b_lab  = p; p += (size_t)8 * 4096 * 8;
    float* c_idx  = p; p += (size_t)8 * 16384;
    float* c_cl   = p; p += (size_t)8 * 16384;
    float* c_fgb  = p; p += (size_t)8 * 16384 * 7;
    float* d_idx  = p; p += (size_t)8 * 4096;
    float* d_cl   = p; p += (size_t)8 * 4096;
    float* d_fgb  = p; p += (size_t)8 * 4096 * 7;

    float* Wt = (float*)d_ws;   // [512][512]

    dim3 gt(16, 16);
    wt_kernel<<<gt, 256, 0, stream>>>(Wb1, Wc1, Wt);

    dim3 gh(128, 8);
    head_kernel<<<gh, 512, 0, stream>>>(
        ctr_feats, Wt, bb1, sb1, tb1, bc1, sc1, tc1,
        Wb2, bb2, Wc2, bc2, ctr_preds, mean_size,
        o_box, o_cls, o_dec);

    dim3 ga(4096 / 256, 8);
    dim3 gc(16384 / 256, 8);
    assign_kernel<<<ga, 256, 0, stream>>>(ctr_preds, 4096, gt_boxes, gt_labels,
        mean_size, gt_ext, 1, 1, a_idx, a_cl, a_fgb, a_lab);
    assign_kernel<<<ga, 256, 0, stream>>>(ctr_origins, 4096, gt_boxes, gt_labels,
        mean_size, org_ext, 0, 1, b_idx, b_cl, b_fgb, b_lab);
    assign_kernel<<<gc, 256, 0, stream>>>(sa_pts0, 16384, gt_boxes, gt_labels,
        mean_size, sa_ext, 1, 0, c_idx, c_cl, c_fgb, nullptr);
    assign_kernel<<<ga, 256, 0, stream>>>(sa_pts1, 4096, gt_boxes, gt_labels,
        mean_size, sa_ext, 0, 0, d_idx, d_cl, d_fgb, nullptr);
}

// Round 6
// 357.263 us; speedup vs baseline: 1.1302x; 1.1302x over previous
//
#include <hip/hip_runtime.h>
#include <hip/hip_bf16.h>
#include <math.h>

using bf16 = __hip_bfloat16;

#define PIF      3.14159265358979323846f
#define TWO_PIF  6.28318530717958647692f
#define BINW     0.52359877559829887308f   // 2*pi/12
#define HBINW    0.26179938779914943654f   // BINW*0.5

// ---------------------------------------------------------------------------
// Sentinel: signals host-side precondition failure through the absmax error.
// ---------------------------------------------------------------------------
__global__ void sentinel_kernel(float* out, float val) {
    out[0] = val;
}

// ---------------------------------------------------------------------------
// K0: transpose W1 of both heads into Wt[c][o] (o<256 = box row o of Wb1,
// o>=256 = cls row o-256 of Wc1). Grid (16,16), 256 threads, 32x32 tiles.
// ---------------------------------------------------------------------------
__global__ __launch_bounds__(256) void wt_kernel(
    const float* __restrict__ Wb1, const float* __restrict__ Wc1,
    float* __restrict__ Wt)               // [512][512]
{
    __shared__ float t[32][33];
    const int tx = threadIdx.x & 31;
    const int ty = threadIdx.x >> 5;      // 0..7
    const int c0 = blockIdx.x * 32;
    const int o0 = blockIdx.y * 32;
#pragma unroll
    for (int r = 0; r < 4; ++r) {
        const int o = o0 + ty + r * 8;
        const float* src = (o < 256) ? (Wb1 + (size_t)o * 512)
                                     : (Wc1 + (size_t)(o - 256) * 512);
        t[ty + r * 8][tx] = src[c0 + tx];
    }
    __syncthreads();
#pragma unroll
    for (int r = 0; r < 4; ++r) {
        const int c = c0 + ty + r * 8;
        Wt[(size_t)c * 512 + o0 + tx] = t[tx][ty + r * 8];
    }
}

// ---------------------------------------------------------------------------
// K1: fully fused heads: L1 (512->512 mids, both heads) in f32, h in LDS,
// L2 (33 outputs) + decode. Grid (128 n-tiles, 8 batches), 512 threads.
// LDS: sW 32K + sX 2K + sH 512*33*4 = 67.6K + sO 4.2K  ~= 106 KiB.
// Round 6: conflict-free flat staging (lane-stride-16B ds_writes) +
// register double-buffering of the staging loads (T14).
// ---------------------------------------------------------------------------
__global__ __launch_bounds__(512) void head_kernel(
    const float* __restrict__ x,          // [8][512][4096]
    const float* __restrict__ Wt,         // [512][512]  Wt[c][o]
    const float* __restrict__ bb1, const float* __restrict__ sb1,
    const float* __restrict__ tb1,
    const float* __restrict__ bc1, const float* __restrict__ sc1,
    const float* __restrict__ tc1,
    const float* __restrict__ Wb2, const float* __restrict__ bb2,
    const float* __restrict__ Wc2, const float* __restrict__ bc2,
    const float* __restrict__ ctr_preds,  // [8][4096][3]
    const float* __restrict__ mean_size,  // [3][3]
    float* __restrict__ out_box,   // [8][4096][30]
    float* __restrict__ out_cls,   // [8][4096][3]
    float* __restrict__ out_dec)   // [8][4096][7]
{
    __shared__ float sW[16 * 512];        // sW[k][o]  (flat = k*512+o)
    __shared__ float sX[16 * 32];         // sX[k][n]  (flat = k*32+n)
    __shared__ float sH[512 * 33];        // sH[o][n], padded to 33
    __shared__ float sO[33 * 32];         // sO[ja][n]

    const int tid = threadIdx.x;
    const int bz  = blockIdx.y;
    const int n0  = blockIdx.x * 32;

    const int ty = tid >> 2;              // 0..127 -> o = ty*4
    const int tx = tid & 3;               // 0..3   -> n = tx*8

    const float* xb = x + (size_t)bz * 512 * 4096;

    // staging addresses: flat, thread-contiguous (conflict-free, coalesced)
    const int xk = tid >> 3;              // 0..63 (only tid<128 used)
    const int xn = (tid & 7) * 4;

    float acc[4][8];
#pragma unroll
    for (int i = 0; i < 4; ++i)
#pragma unroll
        for (int j = 0; j < 8; ++j) acc[i][j] = 0.f;

    // register staging buffers (T14 double-buffer)
    float4 pw0, pw1, pw2, pw3, pxv;

    // prologue: load chunk 0
    {
        const float* wsrc = Wt;           // c0 = 0
        pw0 = *(const float4*)(wsrc + 4 * tid);
        pw1 = *(const float4*)(wsrc + 4 * tid + 2048);
        pw2 = *(const float4*)(wsrc + 4 * tid + 4096);
        pw3 = *(const float4*)(wsrc + 4 * tid + 6144);
        if (tid < 128)
            pxv = *(const float4*)(xb + (size_t)xk * 4096 + n0 + xn);
    }

    for (int c0 = 0; c0 < 512; c0 += 16) {
        // write staged registers to LDS: lane-stride-16B, conflict-free
        *(float4*)&sW[4 * tid]        = pw0;
        *(float4*)&sW[4 * tid + 2048] = pw1;
        *(float4*)&sW[4 * tid + 4096] = pw2;
        *(float4*)&sW[4 * tid + 6144] = pw3;
        if (tid < 128) *(float4*)&sX[4 * tid] = pxv;
        __syncthreads();

        // issue next chunk's loads; latency hides under the 16-k compute
        if (c0 + 16 < 512) {
            const float* wsrc = Wt + (size_t)(c0 + 16) * 512;
            pw0 = *(const float4*)(wsrc + 4 * tid);
            pw1 = *(const float4*)(wsrc + 4 * tid + 2048);
            pw2 = *(const float4*)(wsrc + 4 * tid + 4096);
            pw3 = *(const float4*)(wsrc + 4 * tid + 6144);
            if (tid < 128)
                pxv = *(const float4*)(xb + (size_t)(c0 + 16 + xk) * 4096 + n0 + xn);
        }

#pragma unroll
        for (int k = 0; k < 16; ++k) {
            float a[4], b[8];
            *(float4*)&a[0] = *(const float4*)&sW[k * 512 + ty * 4];
            *(float4*)&b[0] = *(const float4*)&sX[k * 32 + tx * 8];
            *(float4*)&b[4] = *(const float4*)&sX[k * 32 + tx * 8 + 4];
#pragma unroll
            for (int i = 0; i < 4; ++i)
#pragma unroll
                for (int j = 0; j < 8; ++j)
                    acc[i][j] = fmaf(a[i], b[j], acc[i][j]);
        }
        __syncthreads();
    }

    // L1 epilogue: h = relu((acc + b1) * s1 + t1) -> sH (f32)
#pragma unroll
    for (int i = 0; i < 4; ++i) {
        const int o = ty * 4 + i;
        float bv, sv, tv;
        if (o < 256) { bv = bb1[o];       sv = sb1[o];       tv = tb1[o]; }
        else         { bv = bc1[o - 256]; sv = sc1[o - 256]; tv = tc1[o - 256]; }
        float hv[8];
#pragma unroll
        for (int j = 0; j < 8; ++j)
            hv[j] = fmaxf(fmaf(acc[i][j] + bv, sv, tv), 0.f);
        *(float4*)&sH[o * 33 + tx * 8]     = *(float4*)&hv[0];
        *(float4*)&sH[o * 33 + tx * 8 + 4] = *(float4*)&hv[4];
    }
    __syncthreads();

    // L2: sO[ja][n], ja 0..29 box (Wb2/bb2), 30..32 cls (Wc2/bc2)
    for (int p = tid; p < 33 * 32; p += 512) {
        const int ja = p >> 5;
        const int n  = p & 31;
        const float* w2; float bias; int hoff;
        if (ja < 30) { w2 = Wb2 + (size_t)ja * 256;        bias = bb2[ja];      hoff = 0;   }
        else         { w2 = Wc2 + (size_t)(ja - 30) * 256; bias = bc2[ja - 30]; hoff = 256; }
        float a2 = 0.f;
#pragma unroll 8
        for (int o = 0; o < 256; ++o)
            a2 = fmaf(w2[o], sH[(hoff + o) * 33 + n], a2);
        sO[ja * 32 + n] = a2 + bias;
    }
    __syncthreads();

    // epilogue + decode, 1 thread per point
    if (tid < 32) {
        const int nn = tid;
        const size_t gn = (size_t)bz * 4096 + n0 + nn;

        float* ob = out_box + gn * 30;
#pragma unroll
        for (int j = 0; j < 30; ++j) ob[j] = sO[j * 32 + nn];

        const float c0v = sO[30 * 32 + nn];
        const float c1v = sO[31 * 32 + nn];
        const float c2v = sO[32 * 32 + nn];
        out_cls[gn * 3 + 0] = c0v;
        out_cls[gn * 3 + 1] = c1v;
        out_cls[gn * 3 + 2] = c2v;

        int cl = 0; float bv = c0v;
        if (c1v > bv) { bv = c1v; cl = 1; }
        if (c2v > bv) { bv = c2v; cl = 2; }

        const float a0 = mean_size[cl * 3 + 0];
        const float a1 = mean_size[cl * 3 + 1];
        const float a2 = mean_size[cl * 3 + 2];
        const float diag = sqrtf(a0 * a0 + a1 * a1);

        const float px = ctr_preds[gn * 3 + 0];
        const float py = ctr_preds[gn * 3 + 1];
        const float pz = ctr_preds[gn * 3 + 2];

        const float cx = px + sO[0 * 32 + nn] * diag;
        const float cy = py + sO[1 * 32 + nn] * diag;
        const float cz = pz + sO[2 * 32 + nn] * a2;
        const float d0 = expf(sO[3 * 32 + nn]) * a0;
        const float d1 = expf(sO[4 * 32 + nn]) * a1;
        const float d2 = expf(sO[5 * 32 + nn]) * a2;

        int bbin = 0; float lb = sO[6 * 32 + nn];
        for (int k = 1; k < 12; ++k) {
            const float v = sO[(6 + k) * 32 + nn];
            if (v > lb) { lb = v; bbin = k; }
        }
        const float r   = sO[(18 + bbin) * 32 + nn];
        const float ang = ((float)bbin + 0.5f) * BINW + r * HBINW - PIF;

        float* od = out_dec + gn * 7;
        od[0] = cx; od[1] = cy; od[2] = cz;
        od[3] = d0; od[4] = d1; od[5] = d2;
        od[6] = ang;
    }
}

// ---------------------------------------------------------------------------
// K3: assign (points_in_boxes + gather/mask [+ encode]). f32 outputs.
// ---------------------------------------------------------------------------
__global__ __launch_bounds__(256) void assign_kernel(
    const float* __restrict__ pts, int Npts,
    const float* __restrict__ gt_boxes,   // [8][64][7]
    const int*   __restrict__ gt_labels,  // [8][64]
    const float* __restrict__ mean_size,  // [3][3]
    const float* __restrict__ ext,        // [3]
    int ignore, int retlab,
    float* __restrict__ out_idx, float* __restrict__ out_cls,
    float* __restrict__ out_fgb, float* __restrict__ out_lab)
{
    __shared__ float sc[64][4];
    __shared__ float srot[64][2];
    __shared__ float shr[64][4];
    __shared__ float she[64][4];
    __shared__ float sdim[64][4];
    __shared__ float sang[64];
    __shared__ int   slab[64];

    const int tid = threadIdx.x;
    const int b   = blockIdx.y;

    if (tid < 64) {
        const float* bx = gt_boxes + ((size_t)b * 64 + tid) * 7;
        const float cx = bx[0], cy = bx[1], cz = bx[2];
        const float d0 = bx[3], d1 = bx[4], d2 = bx[5], hd = bx[6];
        sc[tid][0] = cx; sc[tid][1] = cy; sc[tid][2] = cz;
        srot[tid][0] = cosf(hd); srot[tid][1] = sinf(hd);
        shr[tid][0] = d0 * 0.5f; shr[tid][1] = d1 * 0.5f; shr[tid][2] = d2 * 0.5f;
        she[tid][0] = (d0 + ext[0]) * 0.5f;
        she[tid][1] = (d1 + ext[1]) * 0.5f;
        she[tid][2] = (d2 + ext[2]) * 0.5f;
        sdim[tid][0] = d0; sdim[tid][1] = d1; sdim[tid][2] = d2;
        sang[tid] = hd;
        slab[tid] = gt_labels[b * 64 + tid];
    }
    __syncthreads();

    const int n = blockIdx.x * 256 + tid;
    if (n >= Npts) return;
    const size_t gp = (size_t)b * Npts + n;

    const float px = pts[gp * 3 + 0];
    const float py = pts[gp * 3 + 1];
    const float pz = pts[gp * 3 + 2];

    int idxr = -1, idxe = -1;
    for (int j = 0; j < 64; ++j) {
        const float rx = px - sc[j][0];
        const float ry = py - sc[j][1];
        const float rz = pz - sc[j][2];
        const float ct = srot[j][0], st = srot[j][1];
        const float lx = rx * ct + ry * st;
        const float ly = -rx * st + ry * ct;
        const float ax = fabsf(lx), ay = fabsf(ly), az = fabsf(rz);
        const bool inr = (ax <= shr[j][0]) && (ay <= shr[j][1]) && (az <= shr[j][2]);
        const bool ine = (ax <= she[j][0]) && (ay <= she[j][1]) && (az <= she[j][2]);
        if (inr && idxr < 0) idxr = j;
        if (ine && idxe < 0) idxe = j;
    }

    const bool fgr = idxr >= 0;
    const bool fge = idxe >= 0;
    int idx, cls;
    bool fg;
    if (ignore) {
        idx = idxr; fg = fgr;
        cls = (fgr != fge) ? -1 : 0;
    } else {
        idx = fgr ? idxr : idxe; fg = fge;
        cls = 0;
    }
    const int ic  = (idx < 0) ? 0 : idx;
    const int lab = slab[ic];
    if (fg) cls = lab;
    fg = fg && (cls != 0);

    out_idx[gp] = (float)idx;
    out_cls[gp] = (float)cls;

    const float m = fg ? 1.f : 0.f;
    float* fb = out_fgb + gp * 7;
    fb[0] = m * sc[ic][0];
    fb[1] = m * sc[ic][1];
    fb[2] = m * sc[ic][2];
    fb[3] = m * sdim[ic][0];
    fb[4] = m * sdim[ic][1];
    fb[5] = m * sdim[ic][2];
    fb[6] = m * sang[ic];

    if (retlab) {
        int lc = lab; if (lc < 1) lc = 1; if (lc > 3) lc = 3;
        const float a0 = mean_size[(lc - 1) * 3 + 0];
        const float a1 = mean_size[(lc - 1) * 3 + 1];
        const float a2 = mean_size[(lc - 1) * 3 + 2];
        const float diag = sqrtf(a0 * a0 + a1 * a1);

        const float ct0 = (sc[ic][0] - px) / diag;
        const float ct1 = (sc[ic][1] - py) / diag;
        const float ct2 = (sc[ic][2] - pz) / a2;
        const float dt0 = logf(fmaxf(sdim[ic][0], 0.001f) / a0);
        const float dt1 = logf(fmaxf(sdim[ic][1], 0.001f) / a1);
        const float dt2 = logf(fmaxf(sdim[ic][2], 0.001f) / a2);

        float angm = fmodf(sang[ic] + PIF, TWO_PIF);
        if (angm < 0.f) angm += TWO_PIF;
        float bbf = floorf(angm / BINW);
        bbf = fminf(fmaxf(bbf, 0.f), 11.f);
        const float rr = (angm - (bbf + 0.5f) * BINW) / HBINW;

        float* ol = out_lab + gp * 8;
        ol[0] = m * ct0;
        ol[1] = m * ct1;
        ol[2] = m * ct2;
        ol[3] = m * dt0;
        ol[4] = m * dt1;
        ol[5] = m * dt2;
        ol[6] = m * bbf;
        ol[7] = m * rr;
    }
}

// ---------------------------------------------------------------------------
extern "C" void kernel_launch(void* const* d_in, const int* in_sizes, int n_in,
                              void* d_out, int out_size, void* d_ws, size_t ws_size,
                              hipStream_t stream) {
    (void)out_size;

    static const int kExp[23] = {
        16777216, 98304, 98304, 393216, 98304, 3584, 512, 9, 3, 3, 3,
        131072, 256, 256, 256, 7680, 30, 131072, 256, 256, 256, 768, 3
    };
    bool ok = (n_in == 23);
    if (ok) for (int i = 0; i < 23; ++i) if (in_sizes[i] != kExp[i]) ok = false;
    if (!ok) {
        sentinel_kernel<<<1, 1, 0, stream>>>((float*)d_out, 1.0e6f);
        return;
    }
    if (ws_size < (size_t)512 * 512 * 4) {   // 1 MiB for Wt
        sentinel_kernel<<<1, 1, 0, stream>>>((float*)d_out, 2.0e6f);
        return;
    }

    const float* ctr_feats   = (const float*)d_in[0];
    const float* ctr_preds   = (const float*)d_in[1];
    const float* ctr_origins = (const float*)d_in[2];
    const float* sa_pts0     = (const float*)d_in[3];
    const float* sa_pts1     = (const float*)d_in[4];
    const float* gt_boxes    = (const float*)d_in[5];
    const int*   gt_labels   = (const int*)d_in[6];
    const float* mean_size   = (const float*)d_in[7];
    const float* gt_ext      = (const float*)d_in[8];
    const float* sa_ext      = (const float*)d_in[9];
    const float* org_ext     = (const float*)d_in[10];
    const float* Wb1 = (const float*)d_in[11];
    const float* bb1 = (const float*)d_in[12];
    const float* sb1 = (const float*)d_in[13];
    const float* tb1 = (const float*)d_in[14];
    const float* Wb2 = (const float*)d_in[15];
    const float* bb2 = (const float*)d_in[16];
    const float* Wc1 = (const float*)d_in[17];
    const float* bc1 = (const float*)d_in[18];
    const float* sc1 = (const float*)d_in[19];
    const float* tc1 = (const float*)d_in[20];
    const float* Wc2 = (const float*)d_in[21];
    const float* bc2 = (const float*)d_in[22];

    float* p = (float*)d_out;
    float* o_box  = p; p += (size_t)8 * 4096 * 30;
    float* o_cls  = p; p += (size_t)8 * 4096 * 3;
    float* o_dec  = p; p += (size_t)8 * 4096 * 7;
    float* a_idx  = p; p += (size_t)8 * 4096;
    float* a_cl   = p; p += (size_t)8 * 4096;
    float* a_fgb  = p; p += (size_t)8 * 4096 * 7;
    float* a_lab  = p; p += (size_t)8 * 4096 * 8;
    float* b_idx  = p; p += (size_t)8 * 4096;
    float* b_cl   = p; p += (size_t)8 * 4096;
    float* b_fgb  = p; p += (size_t)8 * 4096 * 7;
    float* b_lab  = p; p += (size_t)8 * 4096 * 8;
    float* c_idx  = p; p += (size_t)8 * 16384;
    float* c_cl   = p; p += (size_t)8 * 16384;
    float* c_fgb  = p; p += (size_t)8 * 16384 * 7;
    float* d_idx  = p; p += (size_t)8 * 4096;
    float* d_cl   = p; p += (size_t)8 * 4096;
    float* d_fgb  = p; p += (size_t)8 * 4096 * 7;

    float* Wt = (float*)d_ws;   // [512][512]

    dim3 gt(16, 16);
    wt_kernel<<<gt, 256, 0, stream>>>(Wb1, Wc1, Wt);

    dim3 gh(128, 8);
    head_kernel<<<gh, 512, 0, stream>>>(
        ctr_feats, Wt, bb1, sb1, tb1, bc1, sc1, tc1,
        Wb2, bb2, Wc2, bc2, ctr_preds, mean_size,
        o_box, o_cls, o_dec);

    dim3 ga(4096 / 256, 8);
    dim3 gc(16384 / 256, 8);
    assign_kernel<<<ga, 256, 0, stream>>>(ctr_preds, 4096, gt_boxes, gt_labels,
        mean_size, gt_ext, 1, 1, a_idx, a_cl, a_fgb, a_lab);
    assign_kernel<<<ga, 256, 0, stream>>>(ctr_origins, 4096, gt_boxes, gt_labels,
        mean_size, org_ext, 0, 1, b_idx, b_cl, b_fgb, b_lab);
    assign_kernel<<<gc, 256, 0, stream>>>(sa_pts0, 16384, gt_boxes, gt_labels,
        mean_size, sa_ext, 1, 0, c_idx, c_cl, c_fgb, nullptr);
    assign_kernel<<<ga, 256, 0, stream>>>(sa_pts1, 4096, gt_boxes, gt_labels,
        mean_size, sa_ext, 0, 0, d_idx, d_cl, d_fgb, nullptr);
}

// Round 7
// 344.985 us; speedup vs baseline: 1.1705x; 1.0356x over previous
//
#include <hip/hip_runtime.h>
#include <hip/hip_bf16.h>
#include <math.h>

using bf16 = __hip_bfloat16;

#define PIF      3.14159265358979323846f
#define TWO_PIF  6.28318530717958647692f
#define BINW     0.52359877559829887308f   // 2*pi/12
#define HBINW    0.26179938779914943654f   // BINW*0.5

// ---------------------------------------------------------------------------
__global__ void sentinel_kernel(float* out, float val) { out[0] = val; }

// ---------------------------------------------------------------------------
// K0: transpose W1 of both heads into Wt[c][o].
// ---------------------------------------------------------------------------
__global__ __launch_bounds__(256) void wt_kernel(
    const float* __restrict__ Wb1, const float* __restrict__ Wc1,
    float* __restrict__ Wt)               // [512][512]
{
    __shared__ float t[32][33];
    const int tx = threadIdx.x & 31;
    const int ty = threadIdx.x >> 5;      // 0..7
    const int c0 = blockIdx.x * 32;
    const int o0 = blockIdx.y * 32;
#pragma unroll
    for (int r = 0; r < 4; ++r) {
        const int o = o0 + ty + r * 8;
        const float* src = (o < 256) ? (Wb1 + (size_t)o * 512)
                                     : (Wc1 + (size_t)(o - 256) * 512);
        t[ty + r * 8][tx] = src[c0 + tx];
    }
    __syncthreads();
#pragma unroll
    for (int r = 0; r < 4; ++r) {
        const int c = c0 + ty + r * 8;
        Wt[(size_t)c * 512 + o0 + tx] = t[tx][ty + r * 8];
    }
}

// ---------------------------------------------------------------------------
// K1a: L1 GEMM, f32, 128(o) x 128(n) tile, K-chunk 16, 256 threads, 8x8/thread.
// 16 KB LDS -> 4 blocks/CU (launch_bounds(256,4) caps VGPR at 128).
// Conflict-free flat staging + register prefetch (R6 pattern).
// Grid (32 n-tiles, 4 o-tiles, 8 batches). h (f32) -> workspace.
// ---------------------------------------------------------------------------
__global__ __launch_bounds__(256, 4) void l1_kernel(
    const float* __restrict__ x,          // [8][512][4096]
    const float* __restrict__ Wt,         // [512][512]  Wt[c][o]
    const float* __restrict__ bb1, const float* __restrict__ sb1,
    const float* __restrict__ tb1,
    const float* __restrict__ bc1, const float* __restrict__ sc1,
    const float* __restrict__ tc1,
    float* __restrict__ hws)              // [8][512][4096] f32
{
    __shared__ float sA[16 * 128];        // [k][o] flat
    __shared__ float sB[16 * 128];        // [k][n] flat

    const int tid = threadIdx.x;
    const int bx = blockIdx.x;            // n-tile
    const int by = blockIdx.y;            // o-tile
    const int bz = blockIdx.z;            // batch
    const int n0 = bx * 128;
    const int o0 = by * 128;

    const int ty = tid >> 4;              // 0..15 -> o = ty*8
    const int tx = tid & 15;              // 0..15 -> n = tx*8

    // staging: flat idx 4*tid covers [k=tid>>5][col=(tid&31)*4]
    const int aRow = tid >> 5;            // 0..7
    const int aCol = (tid & 31) * 4;      // 0..124

    const float* xb = x + (size_t)bz * 512 * 4096;

    float acc[8][8];
#pragma unroll
    for (int i = 0; i < 8; ++i)
#pragma unroll
        for (int j = 0; j < 8; ++j) acc[i][j] = 0.f;

    float4 pa0, pa1, pb0, pb1;
    // prologue: chunk 0
    pa0 = *(const float4*)(Wt + (size_t)aRow * 512 + o0 + aCol);
    pa1 = *(const float4*)(Wt + (size_t)(aRow + 8) * 512 + o0 + aCol);
    pb0 = *(const float4*)(xb + (size_t)aRow * 4096 + n0 + aCol);
    pb1 = *(const float4*)(xb + (size_t)(aRow + 8) * 4096 + n0 + aCol);

    for (int c0 = 0; c0 < 512; c0 += 16) {
        *(float4*)&sA[4 * tid]        = pa0;
        *(float4*)&sA[4 * tid + 1024] = pa1;
        *(float4*)&sB[4 * tid]        = pb0;
        *(float4*)&sB[4 * tid + 1024] = pb1;
        __syncthreads();

        if (c0 + 16 < 512) {
            const int c = c0 + 16;
            pa0 = *(const float4*)(Wt + (size_t)(c + aRow) * 512 + o0 + aCol);
            pa1 = *(const float4*)(Wt + (size_t)(c + aRow + 8) * 512 + o0 + aCol);
            pb0 = *(const float4*)(xb + (size_t)(c + aRow) * 4096 + n0 + aCol);
            pb1 = *(const float4*)(xb + (size_t)(c + aRow + 8) * 4096 + n0 + aCol);
        }

#pragma unroll
        for (int k = 0; k < 16; ++k) {
            float a[8], b[8];
            *(float4*)&a[0] = *(const float4*)&sA[k * 128 + ty * 8];
            *(float4*)&a[4] = *(const float4*)&sA[k * 128 + ty * 8 + 4];
            *(float4*)&b[0] = *(const float4*)&sB[k * 128 + tx * 8];
            *(float4*)&b[4] = *(const float4*)&sB[k * 128 + tx * 8 + 4];
#pragma unroll
            for (int i = 0; i < 8; ++i)
#pragma unroll
                for (int j = 0; j < 8; ++j)
                    acc[i][j] = fmaf(a[i], b[j], acc[i][j]);
        }
        __syncthreads();
    }

    // epilogue: h = relu((acc + b1)*s1 + t1) -> hws (f32)
    const float* Ba = (by < 2) ? bb1 : bc1;
    const float* Sa = (by < 2) ? sb1 : sc1;
    const float* Ta = (by < 2) ? tb1 : tc1;
    const int bbase = (by < 2) ? o0 : (o0 - 256);

#pragma unroll
    for (int i = 0; i < 8; ++i) {
        const int ol = ty * 8 + i;
        const int bi = bbase + ol;
        const float bv = Ba[bi], sv = Sa[bi], tv = Ta[bi];
        float hv[8];
#pragma unroll
        for (int j = 0; j < 8; ++j)
            hv[j] = fmaxf(fmaf(acc[i][j] + bv, sv, tv), 0.f);
        float* dst = hws + ((size_t)bz * 512 + o0 + ol) * 4096 + n0 + tx * 8;
        *(float4*)dst       = *(float4*)&hv[0];
        *(float4*)(dst + 4) = *(float4*)&hv[4];
    }
}

// ---------------------------------------------------------------------------
// K1b: L2 (33 outs) + decode from f32 h in workspace.
// Grid (128 n-tiles, 8 batches), 256 threads. LDS ~72 KB -> 2 blocks/CU.
// ---------------------------------------------------------------------------
__global__ __launch_bounds__(256) void l2_decode_kernel(
    const float* __restrict__ hws,        // [8][512][4096] f32
    const float* __restrict__ ctr_preds,  // [8][4096][3]
    const float* __restrict__ mean_size,  // [3][3]
    const float* __restrict__ Wb2, const float* __restrict__ bb2,
    const float* __restrict__ Wc2, const float* __restrict__ bc2,
    float* __restrict__ out_box,   // [8][4096][30]
    float* __restrict__ out_cls,   // [8][4096][3]
    float* __restrict__ out_dec)   // [8][4096][7]
{
    __shared__ float sH[512 * 33];        // [o][n], pad 33
    __shared__ float sO[33 * 32];

    const int tid = threadIdx.x;
    const int bz  = blockIdx.y;
    const int n0  = blockIdx.x * 32;

    const float* hb = hws + (size_t)bz * 512 * 4096;
#pragma unroll
    for (int rep = 0; rep < 16; ++rep) {
        const int q = rep * 256 + tid;    // 0..4095
        const int o = q >> 3, n4 = (q & 7) * 4;
        const float4 v = *(const float4*)(hb + (size_t)o * 4096 + n0 + n4);
        *(float4*)&sH[o * 33 + n4] = v;
    }
    __syncthreads();

    const int n = tid & 31, jg = tid >> 5;    // jg 0..7
    for (int ja = jg; ja < 33; ja += 8) {
        const float* w2; float bias; int hoff;
        if (ja < 30) { w2 = Wb2 + (size_t)ja * 256;        bias = bb2[ja];      hoff = 0;   }
        else         { w2 = Wc2 + (size_t)(ja - 30) * 256; bias = bc2[ja - 30]; hoff = 256; }
        float a2 = 0.f;
#pragma unroll 8
        for (int o = 0; o < 256; ++o)
            a2 = fmaf(w2[o], sH[(hoff + o) * 33 + n], a2);
        sO[ja * 32 + n] = a2 + bias;
    }
    __syncthreads();

    if (tid < 32) {
        const int nn = tid;
        const size_t gn = (size_t)bz * 4096 + n0 + nn;

        float* ob = out_box + gn * 30;
#pragma unroll
        for (int j = 0; j < 30; ++j) ob[j] = sO[j * 32 + nn];

        const float c0v = sO[30 * 32 + nn];
        const float c1v = sO[31 * 32 + nn];
        const float c2v = sO[32 * 32 + nn];
        out_cls[gn * 3 + 0] = c0v;
        out_cls[gn * 3 + 1] = c1v;
        out_cls[gn * 3 + 2] = c2v;

        int cl = 0; float bv = c0v;
        if (c1v > bv) { bv = c1v; cl = 1; }
        if (c2v > bv) { bv = c2v; cl = 2; }

        const float a0 = mean_size[cl * 3 + 0];
        const float a1 = mean_size[cl * 3 + 1];
        const float a2 = mean_size[cl * 3 + 2];
        const float diag = sqrtf(a0 * a0 + a1 * a1);

        const float px = ctr_preds[gn * 3 + 0];
        const float py = ctr_preds[gn * 3 + 1];
        const float pz = ctr_preds[gn * 3 + 2];

        const float cx = px + sO[0 * 32 + nn] * diag;
        const float cy = py + sO[1 * 32 + nn] * diag;
        const float cz = pz + sO[2 * 32 + nn] * a2;
        const float d0 = expf(sO[3 * 32 + nn]) * a0;
        const float d1 = expf(sO[4 * 32 + nn]) * a1;
        const float d2 = expf(sO[5 * 32 + nn]) * a2;

        int bbin = 0; float lb = sO[6 * 32 + nn];
        for (int k = 1; k < 12; ++k) {
            const float v = sO[(6 + k) * 32 + nn];
            if (v > lb) { lb = v; bbin = k; }
        }
        const float r   = sO[(18 + bbin) * 32 + nn];
        const float ang = ((float)bbin + 0.5f) * BINW + r * HBINW - PIF;

        float* od = out_dec + gn * 7;
        od[0] = cx; od[1] = cy; od[2] = cz;
        od[3] = d0; od[4] = d1; od[5] = d2;
        od[6] = ang;
    }
}

// ---------------------------------------------------------------------------
// Fallback: fully fused head kernel (verified R6 version), used if ws too small.
// ---------------------------------------------------------------------------
__global__ __launch_bounds__(512) void head_kernel(
    const float* __restrict__ x, const float* __restrict__ Wt,
    const float* __restrict__ bb1, const float* __restrict__ sb1,
    const float* __restrict__ tb1,
    const float* __restrict__ bc1, const float* __restrict__ sc1,
    const float* __restrict__ tc1,
    const float* __restrict__ Wb2, const float* __restrict__ bb2,
    const float* __restrict__ Wc2, const float* __restrict__ bc2,
    const float* __restrict__ ctr_preds, const float* __restrict__ mean_size,
    float* __restrict__ out_box, float* __restrict__ out_cls,
    float* __restrict__ out_dec)
{
    __shared__ float sW[16 * 512];
    __shared__ float sX[16 * 32];
    __shared__ float sH[512 * 33];
    __shared__ float sO[33 * 32];

    const int tid = threadIdx.x;
    const int bz  = blockIdx.y;
    const int n0  = blockIdx.x * 32;
    const int ty = tid >> 2;
    const int tx = tid & 3;
    const float* xb = x + (size_t)bz * 512 * 4096;
    const int xk = tid >> 3;
    const int xn = (tid & 7) * 4;

    float acc[4][8];
#pragma unroll
    for (int i = 0; i < 4; ++i)
#pragma unroll
        for (int j = 0; j < 8; ++j) acc[i][j] = 0.f;

    float4 pw0, pw1, pw2, pw3, pxv;
    {
        const float* wsrc = Wt;
        pw0 = *(const float4*)(wsrc + 4 * tid);
        pw1 = *(const float4*)(wsrc + 4 * tid + 2048);
        pw2 = *(const float4*)(wsrc + 4 * tid + 4096);
        pw3 = *(const float4*)(wsrc + 4 * tid + 6144);
        if (tid < 128)
            pxv = *(const float4*)(xb + (size_t)xk * 4096 + n0 + xn);
    }

    for (int c0 = 0; c0 < 512; c0 += 16) {
        *(float4*)&sW[4 * tid]        = pw0;
        *(float4*)&sW[4 * tid + 2048] = pw1;
        *(float4*)&sW[4 * tid + 4096] = pw2;
        *(float4*)&sW[4 * tid + 6144] = pw3;
        if (tid < 128) *(float4*)&sX[4 * tid] = pxv;
        __syncthreads();

        if (c0 + 16 < 512) {
            const float* wsrc = Wt + (size_t)(c0 + 16) * 512;
            pw0 = *(const float4*)(wsrc + 4 * tid);
            pw1 = *(const float4*)(wsrc + 4 * tid + 2048);
            pw2 = *(const float4*)(wsrc + 4 * tid + 4096);
            pw3 = *(const float4*)(wsrc + 4 * tid + 6144);
            if (tid < 128)
                pxv = *(const float4*)(xb + (size_t)(c0 + 16 + xk) * 4096 + n0 + xn);
        }

#pragma unroll
        for (int k = 0; k < 16; ++k) {
            float a[4], b[8];
            *(float4*)&a[0] = *(const float4*)&sW[k * 512 + ty * 4];
            *(float4*)&b[0] = *(const float4*)&sX[k * 32 + tx * 8];
            *(float4*)&b[4] = *(const float4*)&sX[k * 32 + tx * 8 + 4];
#pragma unroll
            for (int i = 0; i < 4; ++i)
#pragma unroll
                for (int j = 0; j < 8; ++j)
                    acc[i][j] = fmaf(a[i], b[j], acc[i][j]);
        }
        __syncthreads();
    }

#pragma unroll
    for (int i = 0; i < 4; ++i) {
        const int o = ty * 4 + i;
        float bv, sv, tv;
        if (o < 256) { bv = bb1[o];       sv = sb1[o];       tv = tb1[o]; }
        else         { bv = bc1[o - 256]; sv = sc1[o - 256]; tv = tc1[o - 256]; }
        float hv[8];
#pragma unroll
        for (int j = 0; j < 8; ++j)
            hv[j] = fmaxf(fmaf(acc[i][j] + bv, sv, tv), 0.f);
        *(float4*)&sH[o * 33 + tx * 8]     = *(float4*)&hv[0];
        *(float4*)&sH[o * 33 + tx * 8 + 4] = *(float4*)&hv[4];
    }
    __syncthreads();

    for (int p = tid; p < 33 * 32; p += 512) {
        const int ja = p >> 5;
        const int n  = p & 31;
        const float* w2; float bias; int hoff;
        if (ja < 30) { w2 = Wb2 + (size_t)ja * 256;        bias = bb2[ja];      hoff = 0;   }
        else         { w2 = Wc2 + (size_t)(ja - 30) * 256; bias = bc2[ja - 30]; hoff = 256; }
        float a2 = 0.f;
#pragma unroll 8
        for (int o = 0; o < 256; ++o)
            a2 = fmaf(w2[o], sH[(hoff + o) * 33 + n], a2);
        sO[ja * 32 + n] = a2 + bias;
    }
    __syncthreads();

    if (tid < 32) {
        const int nn = tid;
        const size_t gn = (size_t)bz * 4096 + n0 + nn;

        float* ob = out_box + gn * 30;
#pragma unroll
        for (int j = 0; j < 30; ++j) ob[j] = sO[j * 32 + nn];

        const float c0v = sO[30 * 32 + nn];
        const float c1v = sO[31 * 32 + nn];
        const float c2v = sO[32 * 32 + nn];
        out_cls[gn * 3 + 0] = c0v;
        out_cls[gn * 3 + 1] = c1v;
        out_cls[gn * 3 + 2] = c2v;

        int cl = 0; float bv = c0v;
        if (c1v > bv) { bv = c1v; cl = 1; }
        if (c2v > bv) { bv = c2v; cl = 2; }

        const float a0 = mean_size[cl * 3 + 0];
        const float a1 = mean_size[cl * 3 + 1];
        const float a2 = mean_size[cl * 3 + 2];
        const float diag = sqrtf(a0 * a0 + a1 * a1);

        const float px = ctr_preds[gn * 3 + 0];
        const float py = ctr_preds[gn * 3 + 1];
        const float pz = ctr_preds[gn * 3 + 2];

        const float cx = px + sO[0 * 32 + nn] * diag;
        const float cy = py + sO[1 * 32 + nn] * diag;
        const float cz = pz + sO[2 * 32 + nn] * a2;
        const float d0 = expf(sO[3 * 32 + nn]) * a0;
        const float d1 = expf(sO[4 * 32 + nn]) * a1;
        const float d2 = expf(sO[5 * 32 + nn]) * a2;

        int bbin = 0; float lb = sO[6 * 32 + nn];
        for (int k = 1; k < 12; ++k) {
            const float v = sO[(6 + k) * 32 + nn];
            if (v > lb) { lb = v; bbin = k; }
        }
        const float r   = sO[(18 + bbin) * 32 + nn];
        const float ang = ((float)bbin + 0.5f) * BINW + r * HBINW - PIF;

        float* od = out_dec + gn * 7;
        od[0] = cx; od[1] = cy; od[2] = cz;
        od[3] = d0; od[4] = d1; od[5] = d2;
        od[6] = ang;
    }
}

// ---------------------------------------------------------------------------
// K3: assign (points_in_boxes + gather/mask [+ encode]). f32 outputs.
// ---------------------------------------------------------------------------
__global__ __launch_bounds__(256) void assign_kernel(
    const float* __restrict__ pts, int Npts,
    const float* __restrict__ gt_boxes,
    const int*   __restrict__ gt_labels,
    const float* __restrict__ mean_size,
    const float* __restrict__ ext,
    int ignore, int retlab,
    float* __restrict__ out_idx, float* __restrict__ out_cls,
    float* __restrict__ out_fgb, float* __restrict__ out_lab)
{
    __shared__ float sc[64][4];
    __shared__ float srot[64][2];
    __shared__ float shr[64][4];
    __shared__ float she[64][4];
    __shared__ float sdim[64][4];
    __shared__ float sang[64];
    __shared__ int   slab[64];

    const int tid = threadIdx.x;
    const int b   = blockIdx.y;

    if (tid < 64) {
        const float* bx = gt_boxes + ((size_t)b * 64 + tid) * 7;
        const float cx = bx[0], cy = bx[1], cz = bx[2];
        const float d0 = bx[3], d1 = bx[4], d2 = bx[5], hd = bx[6];
        sc[tid][0] = cx; sc[tid][1] = cy; sc[tid][2] = cz;
        srot[tid][0] = cosf(hd); srot[tid][1] = sinf(hd);
        shr[tid][0] = d0 * 0.5f; shr[tid][1] = d1 * 0.5f; shr[tid][2] = d2 * 0.5f;
        she[tid][0] = (d0 + ext[0]) * 0.5f;
        she[tid][1] = (d1 + ext[1]) * 0.5f;
        she[tid][2] = (d2 + ext[2]) * 0.5f;
        sdim[tid][0] = d0; sdim[tid][1] = d1; sdim[tid][2] = d2;
        sang[tid] = hd;
        slab[tid] = gt_labels[b * 64 + tid];
    }
    __syncthreads();

    const int n = blockIdx.x * 256 + tid;
    if (n >= Npts) return;
    const size_t gp = (size_t)b * Npts + n;

    const float px = pts[gp * 3 + 0];
    const float py = pts[gp * 3 + 1];
    const float pz = pts[gp * 3 + 2];

    int idxr = -1, idxe = -1;
    for (int j = 0; j < 64; ++j) {
        const float rx = px - sc[j][0];
        const float ry = py - sc[j][1];
        const float rz = pz - sc[j][2];
        const float ct = srot[j][0], st = srot[j][1];
        const float lx = rx * ct + ry * st;
        const float ly = -rx * st + ry * ct;
        const float ax = fabsf(lx), ay = fabsf(ly), az = fabsf(rz);
        const bool inr = (ax <= shr[j][0]) && (ay <= shr[j][1]) && (az <= shr[j][2]);
        const bool ine = (ax <= she[j][0]) && (ay <= she[j][1]) && (az <= she[j][2]);
        if (inr && idxr < 0) idxr = j;
        if (ine && idxe < 0) idxe = j;
    }

    const bool fgr = idxr >= 0;
    const bool fge = idxe >= 0;
    int idx, cls;
    bool fg;
    if (ignore) {
        idx = idxr; fg = fgr;
        cls = (fgr != fge) ? -1 : 0;
    } else {
        idx = fgr ? idxr : idxe; fg = fge;
        cls = 0;
    }
    const int ic  = (idx < 0) ? 0 : idx;
    const int lab = slab[ic];
    if (fg) cls = lab;
    fg = fg && (cls != 0);

    out_idx[gp] = (float)idx;
    out_cls[gp] = (float)cls;

    const float m = fg ? 1.f : 0.f;
    float* fb = out_fgb + gp * 7;
    fb[0] = m * sc[ic][0];
    fb[1] = m * sc[ic][1];
    fb[2] = m * sc[ic][2];
    fb[3] = m * sdim[ic][0];
    fb[4] = m * sdim[ic][1];
    fb[5] = m * sdim[ic][2];
    fb[6] = m * sang[ic];

    if (retlab) {
        int lc = lab; if (lc < 1) lc = 1; if (lc > 3) lc = 3;
        const float a0 = mean_size[(lc - 1) * 3 + 0];
        const float a1 = mean_size[(lc - 1) * 3 + 1];
        const float a2 = mean_size[(lc - 1) * 3 + 2];
        const float diag = sqrtf(a0 * a0 + a1 * a1);

        const float ct0 = (sc[ic][0] - px) / diag;
        const float ct1 = (sc[ic][1] - py) / diag;
        const float ct2 = (sc[ic][2] - pz) / a2;
        const float dt0 = logf(fmaxf(sdim[ic][0], 0.001f) / a0);
        const float dt1 = logf(fmaxf(sdim[ic][1], 0.001f) / a1);
        const float dt2 = logf(fmaxf(sdim[ic][2], 0.001f) / a2);

        float angm = fmodf(sang[ic] + PIF, TWO_PIF);
        if (angm < 0.f) angm += TWO_PIF;
        float bbf = floorf(angm / BINW);
        bbf = fminf(fmaxf(bbf, 0.f), 11.f);
        const float rr = (angm - (bbf + 0.5f) * BINW) / HBINW;

        float* ol = out_lab + gp * 8;
        ol[0] = m * ct0;
        ol[1] = m * ct1;
        ol[2] = m * ct2;
        ol[3] = m * dt0;
        ol[4] = m * dt1;
        ol[5] = m * dt2;
        ol[6] = m * bbf;
        ol[7] = m * rr;
    }
}

// ---------------------------------------------------------------------------
extern "C" void kernel_launch(void* const* d_in, const int* in_sizes, int n_in,
                              void* d_out, int out_size, void* d_ws, size_t ws_size,
                              hipStream_t stream) {
    (void)out_size;

    static const int kExp[23] = {
        16777216, 98304, 98304, 393216, 98304, 3584, 512, 9, 3, 3, 3,
        131072, 256, 256, 256, 7680, 30, 131072, 256, 256, 256, 768, 3
    };
    bool ok = (n_in == 23);
    if (ok) for (int i = 0; i < 23; ++i) if (in_sizes[i] != kExp[i]) ok = false;
    if (!ok) {
        sentinel_kernel<<<1, 1, 0, stream>>>((float*)d_out, 1.0e6f);
        return;
    }
    const size_t wt_bytes = (size_t)512 * 512 * 4;                 // 1 MiB
    const size_t h_bytes  = (size_t)8 * 512 * 4096 * 4;            // 64 MiB
    if (ws_size < wt_bytes) {
        sentinel_kernel<<<1, 1, 0, stream>>>((float*)d_out, 2.0e6f);
        return;
    }
    const bool big_ws = (ws_size >= wt_bytes + h_bytes);

    const float* ctr_feats   = (const float*)d_in[0];
    const float* ctr_preds   = (const float*)d_in[1];
    const float* ctr_origins = (const float*)d_in[2];
    const float* sa_pts0     = (const float*)d_in[3];
    const float* sa_pts1     = (const float*)d_in[4];
    const float* gt_boxes    = (const float*)d_in[5];
    const int*   gt_labels   = (const int*)d_in[6];
    const float* mean_size   = (const float*)d_in[7];
    const float* gt_ext      = (const float*)d_in[8];
    const float* sa_ext      = (const float*)d_in[9];
    const float* org_ext     = (const float*)d_in[10];
    const float* Wb1 = (const float*)d_in[11];
    const float* bb1 = (const float*)d_in[12];
    const float* sb1 = (const float*)d_in[13];
    const float* tb1 = (const float*)d_in[14];
    const float* Wb2 = (const float*)d_in[15];
    const float* bb2 = (const float*)d_in[16];
    const float* Wc1 = (const float*)d_in[17];
    const float* bc1 = (const float*)d_in[18];
    const float* sc1 = (const float*)d_in[19];
    const float* tc1 = (const float*)d_in[20];
    const float* Wc2 = (const float*)d_in[21];
    const float* bc2 = (const float*)d_in[22];

    float* p = (float*)d_out;
    float* o_box  = p; p += (size_t)8 * 4096 * 30;
    float* o_cls  = p; p += (size_t)8 * 4096 * 3;
    float* o_dec  = p; p += (size_t)8 * 4096 * 7;
    float* a_idx  = p; p += (size_t)8 * 4096;
    float* a_cl   = p; p += (size_t)8 * 4096;
    float* a_fgb  = p; p += (size_t)8 * 4096 * 7;
    float* a_lab  = p; p += (size_t)8 * 4096 * 8;
    float* b_idx  = p; p += (size_t)8 * 4096;
    float* b_cl   = p; p += (size_t)8 * 4096;
    float* b_fgb  = p; p += (size_t)8 * 4096 * 7;
    float* b_lab  = p; p += (size_t)8 * 4096 * 8;
    float* c_idx  = p; p += (size_t)8 * 16384;
    float* c_cl   = p; p += (size_t)8 * 16384;
    float* c_fgb  = p; p += (size_t)8 * 16384 * 7;
    float* d_idx  = p; p += (size_t)8 * 4096;
    float* d_cl   = p; p += (size_t)8 * 4096;
    float* d_fgb  = p; p += (size_t)8 * 4096 * 7;

    float* Wt  = (float*)d_ws;                         // [512][512]
    float* hws = (float*)((char*)d_ws + wt_bytes);     // [8][512][4096] f32

    dim3 gt(16, 16);
    wt_kernel<<<gt, 256, 0, stream>>>(Wb1, Wc1, Wt);

    if (big_ws) {
        dim3 g1(32, 4, 8);
        l1_kernel<<<g1, 256, 0, stream>>>(
            ctr_feats, Wt, bb1, sb1, tb1, bc1, sc1, tc1, hws);
        dim3 g2(128, 8);
        l2_decode_kernel<<<g2, 256, 0, stream>>>(
            hws, ctr_preds, mean_size, Wb2, bb2, Wc2, bc2,
            o_box, o_cls, o_dec);
    } else {
        dim3 gh(128, 8);
        head_kernel<<<gh, 512, 0, stream>>>(
            ctr_feats, Wt, bb1, sb1, tb1, bc1, sc1, tc1,
            Wb2, bb2, Wc2, bc2, ctr_preds, mean_size,
            o_box, o_cls, o_dec);
    }

    dim3 ga(4096 / 256, 8);
    dim3 gc(16384 / 256, 8);
    assign_kernel<<<ga, 256, 0, stream>>>(ctr_preds, 4096, gt_boxes, gt_labels,
        mean_size, gt_ext, 1, 1, a_idx, a_cl, a_fgb, a_lab);
    assign_kernel<<<ga, 256, 0, stream>>>(ctr_origins, 4096, gt_boxes, gt_labels,
        mean_size, org_ext, 0, 1, b_idx, b_cl, b_fgb, b_lab);
    assign_kernel<<<gc, 256, 0, stream>>>(sa_pts0, 16384, gt_boxes, gt_labels,
        mean_size, sa_ext, 1, 0, c_idx, c_cl, c_fgb, nullptr);
    assign_kernel<<<ga, 256, 0, stream>>>(sa_pts1, 4096, gt_boxes, gt_labels,
        mean_size, sa_ext, 0, 0, d_idx, d_cl, d_fgb, nullptr);
}